// Round 3
// baseline (260.106 us; speedup 1.0000x reference)
//
#include <hip/hip_runtime.h>
#include <hip/hip_bf16.h>
#include <stdint.h>

#define KTAPS 9
#define C_IN 128
#define C_OUT 256
#define HW 56
#define PLANE 3136           // 56*56
#define BATCH 32
#define NPX (BATCH * PLANE)  // 100352
#define KTOT 1152            // 9*128
#define PXB 64               // pixels per block (3136 % 64 == 0 -> block never crosses image)
#define NBLK (NPX / PXB)     // 1568 = 8 * 196
#define BLK_PER_XCD (NBLK / 8)

typedef __attribute__((ext_vector_type(8))) _Float16 f16x8;
typedef __attribute__((ext_vector_type(4))) float f32x4;

static __device__ __forceinline__ uint16_t f2h(float f) {
    _Float16 h = (_Float16)f;
    uint16_t u;
    __builtin_memcpy(&u, &h, 2);
    return u;
}

// ---------------- P1: feature NCHW fp32 -> NHWC f16 ----------------
__global__ void k_feat_nhwc(const float* __restrict__ f, unsigned short* __restrict__ fws) {
    __shared__ float tile[C_IN * 57];
    int blk = blockIdx.x;              // b*56 + y
    int b = blk / HW, y = blk % HW;
    const float* src = f + (size_t)b * C_IN * PLANE + y * HW;
    for (int i = threadIdx.x; i < C_IN * HW; i += 256) {
        int c = i / HW, x = i % HW;
        tile[c * 57 + x] = src[(size_t)c * PLANE + x];
    }
    __syncthreads();
    unsigned short* dst = fws + (size_t)blk * HW * C_IN;
    for (int j = threadIdx.x; j < HW * C_IN; j += 256) {
        int x = j >> 7, c = j & 127;
        dst[j] = f2h(tile[c * 57 + x]);
    }
}

// ---------------- P2: weight [OC][IC][3][3] fp32 -> W3 lane-contiguous fragments ----------------
// W3 layout: [t][ks][mtg][lane][8] (f16), i.e. idx = (((t*4+ks)*16+mtg)*64+lane)*8+e
// where oc = mtg*16 + (lane&15), ic = ks*32 + (lane>>4)*8 + e
__global__ void k_weight(const float* __restrict__ w, unsigned short* __restrict__ W3) {
    int idx = blockIdx.x * 256 + threadIdx.x;
    if (idx >= C_OUT * KTOT) return;
    int e = idx & 7;
    int lane = (idx >> 3) & 63;
    int mtg = (idx >> 9) & 15;
    int ks = (idx >> 13) & 3;
    int t = idx >> 15;                 // 0..8
    int oc = mtg * 16 + (lane & 15);
    int ic = ks * 32 + (lane >> 4) * 8 + e;
    int j = t / 3, i = t % 3;
    W3[idx] = f2h(w[((oc * C_IN + ic) * 3 + j) * 3 + i]);
}

// ---------------- P3: offset [B][18][x][y] -> sxy[tc][px] unnormalized coords ----------------
__global__ void k_coords(const float* __restrict__ off, float* __restrict__ sxy) {
    __shared__ float tile[HW * 57];
    int blk = blockIdx.x;              // b*18 + tc
    int b = blk / 18, tc = blk % 18;
    const float* src = off + (size_t)blk * PLANE;
    for (int i = threadIdx.x; i < PLANE; i += 256) {
        int xx = i / HW, yy = i % HW;
        tile[xx * 57 + yy] = src[i];
    }
    __syncthreads();
    float* dst = sxy + (size_t)tc * NPX + (size_t)b * PLANE;
    bool isx = (tc & 1) == 0;
    for (int p = threadIdx.x; p < PLANE; p += 256) {
        int y = p / HW, x = p % HW;
        float v = tile[x * 57 + y];
        float a = isx ? ((float)x - 27.5f) * (1.0f / 27.5f)
                      : ((float)y - 27.5f) * (1.0f / 27.5f);
        dst[p] = (v + a + 1.0f) * 28.0f - 0.5f;
    }
}

// ---------------- P4: fused sample + GEMM, pixel-split waves, NO in-loop barriers ----------------
// Each wave owns 16 pixels (p = wave*16 + l16) x ALL 256 oc. V is wave-private, held in
// registers (cv -> combine -> MFMA B-operand directly). Weights: lane-contiguous W3
// fragments, block-uniform addresses -> L1 broadcasts across the resident waves.
// Pipeline per tap: for each ks { combine cv[ks] (loads issued one FULL tap earlier,
// ~64 MFMA of cover); load 16 A-frags; refill cv[ks] for tap t+1 (issued AFTER A so the
// MFMA's in-order vmcnt wait doesn't drain the slow sample loads); 16 MFMA }.
__global__ __launch_bounds__(256, 2) void k_main(const unsigned short* __restrict__ fws,
                                                 const unsigned short* __restrict__ W3,
                                                 const float* __restrict__ sxy,
                                                 float* __restrict__ out) {
    __shared__ float cs[18][PXB];
    const int tid = threadIdx.x;
    const int wave = tid >> 6, lane = tid & 63;
    const int l16 = lane & 15, grp = lane >> 4;
    const int bid = blockIdx.x;
    const int lbid = (bid & 7) * BLK_PER_XCD + (bid >> 3);    // XCD-chunked swizzle (1568 % 8 == 0)
    const int px0 = lbid * PXB;
    const unsigned short* fb = fws + (size_t)(px0 / PLANE) * (PLANE * C_IN) + grp * 8;

    // stage coords (only LDS use; only barrier)
    for (int i = tid; i < 18 * PXB; i += 256) {
        int tc = i >> 6, pp = i & (PXB - 1);
        cs[tc][pp] = sxy[(size_t)tc * NPX + px0 + pp];
    }
    __syncthreads();

    const int p = wave * 16 + l16;    // this lane's pixel (same across grp)

    f32x4 acc[16];
#pragma unroll
    for (int m = 0; m < 16; m++) acc[m] = (f32x4)0.0f;

    f16x8 cv[4][4];                   // [corner][ks], single-buffered (refilled per-ks after consume)
    float swc[4], swn[4];
    const unsigned short *c00, *c10, *c01, *c11;   // corner row pointers for the NEXT tap to sample

    auto calc_tap = [&](int t, float* sw) {
        float ixv = cs[2 * t][p];
        float iyv = cs[2 * t + 1][p];
        float fx0 = floorf(ixv), fy0 = floorf(iyv);
        float wx1 = ixv - fx0, wy1 = iyv - fy0;
        float wx0 = 1.0f - wx1, wy0 = 1.0f - wy1;
        int ix0 = (int)fx0, iy0 = (int)fy0;
        int ix1 = ix0 + 1, iy1 = iy0 + 1;
        float vx0 = ((unsigned)ix0 < HW) ? 1.0f : 0.0f;
        float vx1 = ((unsigned)ix1 < HW) ? 1.0f : 0.0f;
        float vy0 = ((unsigned)iy0 < HW) ? 1.0f : 0.0f;
        float vy1 = ((unsigned)iy1 < HW) ? 1.0f : 0.0f;
        int xc0 = min(max(ix0, 0), HW - 1), xc1 = min(max(ix1, 0), HW - 1);
        int yc0 = min(max(iy0, 0), HW - 1), yc1 = min(max(iy1, 0), HW - 1);
        const unsigned short* r0 = fb + (size_t)(yc0 * HW) * C_IN;
        const unsigned short* r1 = fb + (size_t)(yc1 * HW) * C_IN;
        c00 = r0 + xc0 * C_IN; c10 = r0 + xc1 * C_IN;
        c01 = r1 + xc0 * C_IN; c11 = r1 + xc1 * C_IN;
        sw[0] = wx0 * wy0 * vx0 * vy0;
        sw[1] = wx1 * wy0 * vx1 * vy0;
        sw[2] = wx0 * wy1 * vx0 * vy1;
        sw[3] = wx1 * wy1 * vx1 * vy1;
    };

    auto sample_ks = [&](int ks) {
        cv[0][ks] = *(const f16x8*)(c00 + ks * 32);
        cv[1][ks] = *(const f16x8*)(c10 + ks * 32);
        cv[2][ks] = *(const f16x8*)(c01 + ks * 32);
        cv[3][ks] = *(const f16x8*)(c11 + ks * 32);
    };

    // prologue: tap 0 addresses + all 16 sample loads in flight
    calc_tap(0, swc);
#pragma unroll
    for (int ks = 0; ks < 4; ks++) sample_ks(ks);

#pragma unroll
    for (int t = 0; t < KTAPS; t++) {
        const bool more = (t < KTAPS - 1);
        if (more) calc_tap(t + 1, swn);          // old pointers already fully consumed
#pragma unroll
        for (int ks = 0; ks < 4; ks++) {
            // consume cv[*][ks] — these loads were issued one full tap ago
            f16x8 v = cv[0][ks] * (f16x8)(_Float16)swc[0]
                    + cv[1][ks] * (f16x8)(_Float16)swc[1]
                    + cv[2][ks] * (f16x8)(_Float16)swc[2]
                    + cv[3][ks] * (f16x8)(_Float16)swc[3];
            // A-frags for (t,ks): block-uniform 8 KB run, L1-broadcast across waves.
            // Issued BEFORE the sample refill so the MFMA's vmcnt wait (in-order)
            // does not have to drain the slow sample loads.
            const unsigned short* wb = W3 + (size_t)(t * 4 + ks) * 8192 + lane * 8;
            f16x8 af[16];
#pragma unroll
            for (int mtg = 0; mtg < 16; mtg++)
                af[mtg] = *(const f16x8*)(wb + mtg * 512);
            if (more) sample_ks(ks);             // refill cv[*][ks] for tap t+1
#pragma unroll
            for (int mtg = 0; mtg < 16; mtg++)
                acc[mtg] = __builtin_amdgcn_mfma_f32_16x16x32_f16(af[mtg], v, acc[mtg], 0, 0, 0);
        }
        if (more) {
#pragma unroll
            for (int c = 0; c < 4; c++) swc[c] = swn[c];
        }
    }

    // epilogue: pixel = px0 + p (col = l16), oc = mtg*16 + grp*4 + r (row)
    {
        int bb = px0 / PLANE;
        int rr = px0 - bb * PLANE + p;
        float* ob = out + (size_t)bb * C_OUT * PLANE + rr;
#pragma unroll
        for (int mtg = 0; mtg < 16; mtg++) {
#pragma unroll
            for (int r = 0; r < 4; r++) {
                int oc = mtg * 16 + grp * 4 + r;
                ob[(size_t)oc * PLANE] = acc[mtg][r];
            }
        }
    }
}

extern "C" void kernel_launch(void* const* d_in, const int* in_sizes, int n_in,
                              void* d_out, int out_size, void* d_ws, size_t ws_size,
                              hipStream_t stream) {
    const float* feature = (const float*)d_in[0];
    const float* offset = (const float*)d_in[1];
    const float* weight = (const float*)d_in[2];
    float* out = (float*)d_out;

    char* ws = (char*)d_ws;
    unsigned short* fws = (unsigned short*)ws;                          // 25,690,112 B
    unsigned short* W3 = (unsigned short*)(ws + 25690112);              // 589,824 B
    float* sxy = (float*)(ws + 25690112 + 589824);                      // 7,225,344 B

    k_feat_nhwc<<<BATCH * HW, 256, 0, stream>>>(feature, fws);
    k_weight<<<(C_OUT * KTOT + 255) / 256, 256, 0, stream>>>(weight, W3);
    k_coords<<<BATCH * 18, 256, 0, stream>>>(offset, sxy);
    k_main<<<NBLK, 256, 0, stream>>>(fws, W3, sxy, out);
}